// Round 15
// baseline (282.526 us; speedup 1.0000x reference)
//
#include <hip/hip_runtime.h>
#include <hip/hip_bf16.h>
#include <cstdint>
#include <cstddef>

using bf16 = __hip_bfloat16;
typedef __attribute__((ext_vector_type(8))) short bf16x8;
typedef __attribute__((ext_vector_type(4))) float f32x4;

#define TOKENS 4096
#define DMODEL 1024
#define DFF    4096
#define SEQ    2048
#define NHEAD  16
#define HDIM   64
#define KVBLK  64
#define NT     (SEQ / KVBLK)
#define QSCALE 0.1803368801111f   /* 0.125 * log2(e): folded into Q at QKV epilogue */

__device__ __forceinline__ void async16(const void* g, void* l) {
  __builtin_amdgcn_global_load_lds(
      (const __attribute__((address_space(1))) void*)g,
      (__attribute__((address_space(3))) void*)l, 16, 0, 0);
}

__device__ __forceinline__ f32x4 mfma16(bf16x8 a, bf16x8 b, f32x4 c) {
  return __builtin_amdgcn_mfma_f32_16x16x32_bf16(a, b, c, 0, 0, 0);
}

// native v_exp_f32: computes 2^x (single TRANS-pipe op, no OCML slow path)
__device__ __forceinline__ float exp2_fast(float x) {
  float r;
  asm("v_exp_f32 %0, %1" : "=v"(r) : "v"(x));
  return r;
}

// exact-GELU via A&S 7.1.26 erf (|eps| <= 1.5e-7), no library call
__device__ __forceinline__ float gelu_fast(float x) {
  const float z = fabsf(x) * 0.70710678118f;
  const float t = __builtin_amdgcn_rcpf(1.f + 0.3275911f * z);
  float p = 1.061405429f;
  p = p * t - 1.453152027f;
  p = p * t + 1.421413741f;
  p = p * t - 0.284496736f;
  p = p * t + 0.254829592f;
  const float e = exp2_fast(-z * z * 1.44269504089f);
  float erf = 1.f - p * t * e;
  erf = (x < 0.f) ? -erf : erf;
  return 0.5f * x * (1.f + erf);
}

// ---------------- fused prep: 4 weight transposes (fp32 KxN -> bf16 NxK) + x cast ----------------
__global__ __launch_bounds__(256)
void prep_k(const float* __restrict__ wqkv, const float* __restrict__ wout,
            const float* __restrict__ wff1, const float* __restrict__ wff2,
            bf16* __restrict__ dqkv, bf16* __restrict__ dout,
            bf16* __restrict__ dff1, bf16* __restrict__ dff2,
            const float* __restrict__ x, bf16* __restrict__ xb) {
  const int b = blockIdx.x, t = threadIdx.x;
  if (b >= 12288) {   // ---- cast x -> bf16 ----
    const int i = (b - 12288) * 1024 + t * 4;
    float4 v = *(const float4*)(x + i);
    bf16* d = xb + i;
    d[0] = __float2bfloat16(v.x); d[1] = __float2bfloat16(v.y);
    d[2] = __float2bfloat16(v.z); d[3] = __float2bfloat16(v.w);
    return;
  }
  const float* src; bf16* dst; int K, N, local;
  if (b < 3072)      { src = wqkv; dst = dqkv; K = 1024; N = 3072; local = b; }
  else if (b < 4096) { src = wout; dst = dout; K = 1024; N = 1024; local = b - 3072; }
  else if (b < 8192) { src = wff1; dst = dff1; K = 1024; N = 4096; local = b - 4096; }
  else               { src = wff2; dst = dff2; K = 4096; N = 1024; local = b - 8192; }
  const int nx = N >> 5;
  const int tiley = local / nx, tilex = local - tiley * nx;
  const int nt = tilex * 32, kt = tiley * 32;
  const int tx = t & 31, ty = t >> 5;   // 32 x 8
  __shared__ float tile[32][33];
  #pragma unroll
  for (int i = 0; i < 32; i += 8)
    tile[ty + i][tx] = src[(size_t)(kt + ty + i) * N + nt + tx];
  __syncthreads();
  #pragma unroll
  for (int i = 0; i < 32; i += 8)
    dst[(size_t)(nt + ty + i) * K + kt + tx] = __float2bfloat16(tile[tx][ty + i]);
}

// ---------------- GEMM: C[M][N] = A[M][K] * Bt[N][K] + bias, fused epilogue ----------------
// 2-phase pipeline (best-measured, R7/R8/R11): double-buffered LDS, stage(t+1)
// issued BEFORE compute(t), single vmcnt(0)+barrier per K-tile, BK=32.
// BN=64 (24KB LDS -> 6 blocks/CU resident) used for ALL GEMMs per R15 theory:
// throughput at these shapes tracks resident blocks/CU (drain-stall overlap).
// Split-K via gridDim.z; EPI 3 writes RAW fp32 partial to outf/outf2.
// EPI 0: QKV scatter (Q pre-scaled by QSCALE).  EPI 2: bf16 out = gelu(v).
template <int EPI, int BN>
__global__ __launch_bounds__(256, 2)
void gemm_bt(const bf16* __restrict__ A, const bf16* __restrict__ Bt,
             const float* __restrict__ bias, int M, int N, int K,
             float* __restrict__ outf, float* __restrict__ outf2,
             bf16* __restrict__ outb,
             bf16* __restrict__ Qb, bf16* __restrict__ Kb, bf16* __restrict__ Vtb) {
  constexpr int MR = (BN == 128) ? 4 : 2;
  __shared__ bf16 Al[2][128 * 32];
  __shared__ bf16 Bl[2][BN * 32];
  const int t = threadIdx.x;
  const int nwg = gridDim.x * gridDim.y;
  const int flat = blockIdx.y * gridDim.x + blockIdx.x;
  const int swz = (flat & 7) * (nwg >> 3) + (flat >> 3);
  const int bm = (swz / gridDim.x) * 128, bn = (swz % gridDim.x) * BN;
  const int kz = blockIdx.z;
  const int Ksub = K / gridDim.z;
  const int kb0 = kz * Ksub;
  const int wid = t >> 6, lane = t & 63, g = lane >> 4, r = lane & 15;
  const int wr = (BN == 128) ? (wid >> 1) * 64 : wid * 32;
  const int wc = (BN == 128) ? (wid & 1) * 64 : 0;

  const f32x4 zero = {0.f, 0.f, 0.f, 0.f};
  f32x4 acc[MR][4];
  #pragma unroll
  for (int i = 0; i < MR; i++)
    #pragma unroll
    for (int j = 0; j < 4; j++) acc[i][j] = zero;

  const int ar0 = t >> 2, ac = (t & 3) * 8;
  const int ar1 = ar0 + 64;
  const int ach0 = t * 16, ach1 = ach0 + 4096;

  const int NK = Ksub >> 5;
  #define STAGE(ktile, pb)                                                          \
    do {                                                                            \
      const int kk = kb0 + ((ktile) << 5);                                          \
      async16(A + (size_t)(bm + ar0) * K + kk + ac, (char*)Al[pb] + ach0);          \
      async16(A + (size_t)(bm + ar1) * K + kk + ac, (char*)Al[pb] + ach1);          \
      async16(Bt + (size_t)(bn + ar0) * K + kk + ac, (char*)Bl[pb] + ach0);         \
      if constexpr (BN == 128)                                                      \
        async16(Bt + (size_t)(bn + ar1) * K + kk + ac, (char*)Bl[pb] + ach1);       \
    } while (0)

  STAGE(0, 0);
  asm volatile("s_waitcnt vmcnt(0)" ::: "memory");
  __builtin_amdgcn_s_barrier();

  #pragma unroll 1
  for (int it = 0; it < NK; ++it) {
    const int cur = it & 1;
    if (it + 1 < NK) STAGE(it + 1, cur ^ 1);
    bf16x8 af[MR], bfr[4];
    #pragma unroll
    for (int mt = 0; mt < MR; mt++)
      af[mt] = *(const bf16x8*)&Al[cur][(wr + mt * 16 + r) * 32 + 8 * g];
    #pragma unroll
    for (int nt = 0; nt < 4; nt++)
      bfr[nt] = *(const bf16x8*)&Bl[cur][(wc + nt * 16 + r) * 32 + 8 * g];
    #pragma unroll
    for (int mt = 0; mt < MR; mt++)
      #pragma unroll
      for (int nt = 0; nt < 4; nt++)
        acc[mt][nt] = mfma16(af[mt], bfr[nt], acc[mt][nt]);
    __builtin_amdgcn_sched_barrier(0);
    asm volatile("s_waitcnt vmcnt(0)" ::: "memory");
    __builtin_amdgcn_s_barrier();
  }
  #undef STAGE

  float* __restrict__ pdst = kz ? outf2 : outf;
  #pragma unroll
  for (int nt = 0; nt < 4; nt++) {
    const int col = bn + wc + nt * 16 + r;
    const float bv = (EPI == 3) ? 0.f : bias[col];
    #pragma unroll
    for (int mt = 0; mt < MR; mt++) {
      #pragma unroll
      for (int j = 0; j < 4; j++) {
        const int row = bm + wr + mt * 16 + 4 * g + j;
        float v = acc[mt][nt][j] + bv;
        if constexpr (EPI == 0) {
          const int part = col >> 10, hd = col & 1023, h = hd >> 6, d = hd & 63;
          const int b_ = row >> 11, s_ = row & 2047;
          if (part == 0) {
            Qb[((size_t)(b_ * NHEAD + h) * SEQ + s_) * HDIM + d] =
                __float2bfloat16(v * QSCALE);
          } else if (part == 1) {
            Kb[((size_t)(b_ * NHEAD + h) * SEQ + s_) * HDIM + d] = __float2bfloat16(v);
          } else {
            Vtb[((size_t)(b_ * NHEAD + h) * HDIM + d) * SEQ + s_] = __float2bfloat16(v);
          }
        } else if constexpr (EPI == 3) {
          pdst[(size_t)row * N + col] = v;           // raw fp32 partial
        } else {
          outb[(size_t)row * N + col] = __float2bfloat16(gelu_fast(v));
        }
      }
    }
  }
}

// ---------------- flash attention (R9-measured best): LDS-staged, double-buffered ----------------
// grid 512 (XCD-chunked -> (bh,qb)), 256 thr = 4 waves, 32 q rows/wave (2 fragment
// sets of 16), KVBLK=64.  Q pre-scaled by 0.125*log2e -> softmax in exp2 domain
// (native v_exp_f32).  Defer-max (T13, THR=8) per set.
__global__ __launch_bounds__(256, 3)
void attn_k(const bf16* __restrict__ Q, const bf16* __restrict__ Km,
            const bf16* __restrict__ Vt, bf16* __restrict__ O) {
  __shared__ bf16 Kl[2][KVBLK * 64];   // 16 KB
  __shared__ bf16 Vl[2][KVBLK * 64];   // 16 KB
  __shared__ bf16 P[4][32 * 64];       // 16 KB: per-wave 32-row P, XOR-swizzled
  const int b = blockIdx.x;
  const int bswz = (b & 7) * 64 + (b >> 3);   // 512 blocks, 64/XCD -> 4 heads/XCD
  const int bh = bswz >> 4, qb = bswz & 15;
  const int t = threadIdx.x, wid = t >> 6, lane = t & 63, g = lane >> 4, r = lane & 15;
  const int q0 = qb * 128 + wid * 32;
  const bf16* Qp = Q + (size_t)bh * SEQ * HDIM;
  const char* Kc = (const char*)(Km + (size_t)bh * SEQ * HDIM);
  const char* Vc = (const char*)(Vt + (size_t)bh * HDIM * SEQ);

  bf16x8 qf[2][2];
  #pragma unroll
  for (int s = 0; s < 2; s++) {
    qf[s][0] = *(const bf16x8*)&Qp[(q0 + 16 * s + r) * HDIM + 8 * g];
    qf[s][1] = *(const bf16x8*)&Qp[(q0 + 16 * s + r) * HDIM + 8 * g + 32];
  }

  const int o0 = wid * 2048 + lane * 16, o1 = o0 + 1024;
  const int cs0 = ((((o0 >> 4) & 7) ^ ((o0 >> 7) & 7)) << 4);
  const int cs1 = ((((o1 >> 4) & 7) ^ ((o1 >> 7) & 7)) << 4);
  const int kso0 = (o0 & ~127) + cs0, kso1 = (o1 & ~127) + cs1;
  const int vso0 = (o0 >> 7) * (SEQ * 2) + cs0, vso1 = (o1 >> 7) * (SEQ * 2) + cs1;

  const f32x4 zero = {0.f, 0.f, 0.f, 0.f};
  f32x4 oacc[2][4];
  #pragma unroll
  for (int s = 0; s < 2; s++)
    #pragma unroll
    for (int i = 0; i < 4; i++) oacc[s][i] = zero;
  float mrow[2] = {-1e30f, -1e30f}, lrow[2] = {0.f, 0.f};
  bf16* pl = P[wid];
  const int cA = ((g ^ (r & 7)) << 3), cB = (((g + 4) ^ (r & 7)) << 3);

  {
    char* kd = (char*)Kl[0]; char* vd = (char*)Vl[0];
    async16(Kc + kso0, kd + o0); async16(Kc + kso1, kd + o1);
    async16(Vc + vso0, vd + o0); async16(Vc + vso1, vd + o1);
  }

  #pragma unroll 1
  for (int tt = 0; tt < NT; ++tt) {
    if (tt + 1 < NT) {
      const char* ks = Kc + (tt + 1) * (KVBLK * HDIM * 2);
      const char* vs = Vc + (tt + 1) * (KVBLK * 2);
      char* kd = (char*)Kl[(tt + 1) & 1]; char* vd = (char*)Vl[(tt + 1) & 1];
      async16(ks + kso0, kd + o0); async16(ks + kso1, kd + o1);
      async16(vs + vso0, vd + o0); async16(vs + vso1, vd + o1);
      asm volatile("s_waitcnt vmcnt(4)" ::: "memory");
    } else {
      asm volatile("s_waitcnt vmcnt(0)" ::: "memory");
    }
    __builtin_amdgcn_sched_barrier(0);
    __builtin_amdgcn_s_barrier();
    __builtin_amdgcn_sched_barrier(0);

    const bf16* kbuf = Kl[tt & 1];
    const bf16* vbuf = Vl[tt & 1];

    // ---- QK^T (swapped): each K fragment pair feeds BOTH q-sets ----
    f32x4 sacc[2][4];
    #pragma unroll
    for (int kt = 0; kt < 4; kt++) {
      const bf16* krow = kbuf + (kt * 16 + r) * 64;
      bf16x8 ka = *(const bf16x8*)&krow[cA];
      bf16x8 kb = *(const bf16x8*)&krow[cB];
      #pragma unroll
      for (int s = 0; s < 2; s++) {
        f32x4 sc = mfma16(ka, qf[s][0], zero);
        sacc[s][kt] = mfma16(kb, qf[s][1], sc);
      }
    }

    // ---- per-set softmax (exp2 domain) + P write ----
    bool grow[2];
    float corr[2];
    #pragma unroll
    for (int s = 0; s < 2; s++) {
      float m0 = fmaxf(fmaxf(sacc[s][0][0], sacc[s][0][1]), fmaxf(sacc[s][0][2], sacc[s][0][3]));
      float m1 = fmaxf(fmaxf(sacc[s][1][0], sacc[s][1][1]), fmaxf(sacc[s][1][2], sacc[s][1][3]));
      float m2 = fmaxf(fmaxf(sacc[s][2][0], sacc[s][2][1]), fmaxf(sacc[s][2][2], sacc[s][2][3]));
      float m3 = fmaxf(fmaxf(sacc[s][3][0], sacc[s][3][1]), fmaxf(sacc[s][3][2], sacc[s][3][3]));
      float mx = fmaxf(fmaxf(m0, m1), fmaxf(m2, m3));
      mx = fmaxf(mx, __shfl_xor(mx, 16));
      mx = fmaxf(mx, __shfl_xor(mx, 32));
      grow[s] = !__all(mx <= mrow[s] + 8.f);
      corr[s] = 1.f;
      if (grow[s]) {
        const float mn = fmaxf(mrow[s], mx);
        corr[s] = exp2_fast(mrow[s] - mn);
        mrow[s] = mn;
      }
      float sum = 0.f;
      #pragma unroll
      for (int kt = 0; kt < 4; kt++) {
        bf16 pk[4];
        #pragma unroll
        for (int j = 0; j < 4; j++) {
          const float p = exp2_fast(sacc[s][kt][j] - mrow[s]);
          pk[j] = __float2bfloat16(p);
          sum += p;
        }
        const int pc = (((kt * 2 + (g >> 1)) ^ (r & 7)) << 4) + ((g & 1) << 3);
        *(short4*)((char*)pl + (16 * s + r) * 128 + pc) = *(const short4*)pk;
      }
      sum += __shfl_xor(sum, 16);
      sum += __shfl_xor(sum, 32);
      lrow[s] = lrow[s] * corr[s] + sum;
    }

    asm volatile("s_waitcnt lgkmcnt(0)" ::: "memory");
    __builtin_amdgcn_sched_barrier(0);
    bf16x8 pf[2][2];
    #pragma unroll
    for (int s = 0; s < 2; s++) {
      pf[s][0] = *(const bf16x8*)((const char*)pl + (16 * s + r) * 128 + (cA << 1));
      pf[s][1] = *(const bf16x8*)((const char*)pl + (16 * s + r) * 128 + (cB << 1));
    }

    #pragma unroll
    for (int s = 0; s < 2; s++) {
      if (grow[s]) {   // wave-uniform: rescale O only when this set's max grew
        float cq[4];
        #pragma unroll
        for (int j = 0; j < 4; j++) cq[j] = __shfl(corr[s], 4 * g + j);
        #pragma unroll
        for (int dt = 0; dt < 4; dt++)
          #pragma unroll
          for (int j = 0; j < 4; j++) oacc[s][dt][j] *= cq[j];
      }
    }

    // ---- PV: each V fragment pair feeds BOTH q-sets ----
    #pragma unroll
    for (int dt = 0; dt < 4; dt++) {
      const bf16* vrow = vbuf + (dt * 16 + r) * 64;
      bf16x8 v0 = *(const bf16x8*)&vrow[cA];
      bf16x8 v1 = *(const bf16x8*)&vrow[cB];
      #pragma unroll
      for (int s = 0; s < 2; s++) {
        oacc[s][dt] = mfma16(pf[s][0], v0, oacc[s][dt]);
        oacc[s][dt] = mfma16(pf[s][1], v1, oacc[s][dt]);
      }
    }
    __builtin_amdgcn_sched_barrier(0);
    __builtin_amdgcn_s_barrier();
  }

  const int b_ = bh >> 4, h = bh & 15;
  #pragma unroll
  for (int s = 0; s < 2; s++) {
    float lq[4];
    #pragma unroll
    for (int j = 0; j < 4; j++) lq[j] = __shfl(lrow[s], 4 * g + j);
    #pragma unroll
    for (int dt = 0; dt < 4; dt++)
      #pragma unroll
      for (int j = 0; j < 4; j++) {
        const int tok = b_ * SEQ + q0 + 16 * s + 4 * g + j;
        O[(size_t)tok * DMODEL + h * HDIM + dt * 16 + r] =
            __float2bfloat16(oacc[s][dt][j] / lq[j]);
      }
  }
}

// ---------------- fused split-K reduce + bias + residual + LayerNorm ----------------
// RB=0: resid fp32; RB=1: resid bf16.  v = p0+p1+bias2+resid; LN(v)*g+b.
template <int RB>
__global__ __launch_bounds__(256)
void ln_fused_k(const float* __restrict__ p0, const float* __restrict__ p1,
                const float* __restrict__ bias2, const void* __restrict__ resid,
                const float* __restrict__ gw, const float* __restrict__ bw,
                float* __restrict__ outf, bf16* __restrict__ outb) {
  const int row = blockIdx.x, t = threadIdx.x;
  const size_t base = (size_t)row * DMODEL + t * 4;
  const float4 a = *(const float4*)(p0 + base);
  const float4 b = *(const float4*)(p1 + base);
  float rr0, rr1, rr2, rr3;
  if constexpr (RB) {
    const bf16* rp = (const bf16*)resid + base;
    short4 rv = *(const short4*)rp;
    rr0 = __bfloat162float(((const bf16*)&rv)[0]);
    rr1 = __bfloat162float(((const bf16*)&rv)[1]);
    rr2 = __bfloat162float(((const bf16*)&rv)[2]);
    rr3 = __bfloat162float(((const bf16*)&rv)[3]);
  } else {
    const float4 rv = *(const float4*)((const float*)resid + base);
    rr0 = rv.x; rr1 = rv.y; rr2 = rv.z; rr3 = rv.w;
  }
  const float4 bb = *(const float4*)(bias2 + t * 4);
  float4 v;
  v.x = a.x + b.x + rr0 + bb.x;
  v.y = a.y + b.y + rr1 + bb.y;
  v.z = a.z + b.z + rr2 + bb.z;
  v.w = a.w + b.w + rr3 + bb.w;
  float s = v.x + v.y + v.z + v.w;
  float s2 = v.x * v.x + v.y * v.y + v.z * v.z + v.w * v.w;
  #pragma unroll
  for (int m = 1; m < 64; m <<= 1) { s += __shfl_xor(s, m); s2 += __shfl_xor(s2, m); }
  __shared__ float red[8];
  const int wid = t >> 6, lane = t & 63;
  if (lane == 0) { red[wid] = s; red[4 + wid] = s2; }
  __syncthreads();
  s = red[0] + red[1] + red[2] + red[3];
  s2 = red[4] + red[5] + red[6] + red[7];
  const float mu = s * (1.f / DMODEL);
  const float rstd = rsqrtf(s2 * (1.f / DMODEL) - mu * mu + 1e-5f);
  const float4 gv = *(const float4*)(gw + t * 4);
  const float4 bv = *(const float4*)(bw + t * 4);
  float o0 = (v.x - mu) * rstd * gv.x + bv.x;
  float o1 = (v.y - mu) * rstd * gv.y + bv.y;
  float o2 = (v.z - mu) * rstd * gv.z + bv.z;
  float o3 = (v.w - mu) * rstd * gv.w + bv.w;
  if (outf) {
    float4 ov = {o0, o1, o2, o3};
    *(float4*)(outf + base) = ov;
  }
  if (outb) {
    bf16* p = outb + base;
    p[0] = __float2bfloat16(o0); p[1] = __float2bfloat16(o1);
    p[2] = __float2bfloat16(o2); p[3] = __float2bfloat16(o3);
  }
}

extern "C" void kernel_launch(void* const* d_in, const int* in_sizes, int n_in,
                              void* d_out, int out_size, void* d_ws, size_t ws_size,
                              hipStream_t stream) {
  const float* x     = (const float*)d_in[0];
  const float* w_qkv = (const float*)d_in[1];
  const float* b_qkv = (const float*)d_in[2];
  const float* w_out = (const float*)d_in[3];
  const float* b_out = (const float*)d_in[4];
  const float* w_ff1 = (const float*)d_in[5];
  const float* b_ff1 = (const float*)d_in[6];
  const float* w_ff2 = (const float*)d_in[7];
  const float* b_ff2 = (const float*)d_in[8];
  const float* ln1_g = (const float*)d_in[9];
  const float* ln1_b = (const float*)d_in[10];
  const float* ln2_g = (const float*)d_in[11];
  const float* ln2_b = (const float*)d_in[12];
  float* out = (float*)d_out;

  // workspace layout (heavy aliasing; all stream-ordered):
  //   [0,16M)      wqkvT+woutT+wff1T  -> later FF2 partial p1 (dead by then)
  //   [24M,56M)    Qb/Kb/Vtb/xob      -> Qb+Kb reused as out-proj partial p0; hb aliases
  //   [56M,72M)    y region: out-proj partial p1, then FF2 partial p0
  //   [88M,96M)    x1b (LN1 output, bf16 — also LN2 residual)
  char* base = (char*)d_ws;
  bf16* wqkvT = (bf16*)(base);                 //  6291456 : 3072x1024
  bf16* woutT = (bf16*)(base + 6291456);       //  2097152 : 1024x1024
  bf16* wff1T = (bf16*)(base + 8388608);       //  8388608 : 4096x1024
  bf16* wff2T = (bf16*)(base + 16777216);      //  8388608 : 1024x4096
  bf16* Qb    = (bf16*)(base + 25165824);      //  8388608
  bf16* Kb    = (bf16*)(base + 33554432);      //  8388608
  bf16* Vtb   = (bf16*)(base + 41943040);      //  8388608
  bf16* xob   = (bf16*)(base + 50331648);      //  8388608 : x_bf16, later attn-out bf16
  bf16* hb    = (bf16*)(base + 25165824);      // 33554432 : aliases Qb..xob (dead by FF1)
  float* pA0  = (float*)(base + 25165824);     // 16777216 : out-proj partial 0 (over Qb+Kb)
  float* pA1  = (float*)(base + 58720256);     // 16777216 : out-proj partial 1
  float* pB0  = (float*)(base + 58720256);     // 16777216 : FF2 partial 0
  float* pB1  = (float*)(base);                // 16777216 : FF2 partial 1 (over weights)
  bf16* x1b   = (bf16*)(base + 92274688);      //  8388608
  (void)in_sizes; (void)n_in; (void)out_size; (void)ws_size;

  // fused prep: all 4 weight transposes + x cast in ONE launch
  prep_k<<<dim3(16384), 256, 0, stream>>>(w_qkv, w_out, w_ff1, w_ff2,
                                          wqkvT, woutT, wff1T, wff2T, x, xob);

  // QKV projection + scatter (Q pre-scaled) — BN=64: grid 1536 = 6 blocks/CU
  gemm_bt<0, 64><<<dim3(3072 / 64, TOKENS / 128), 256, 0, stream>>>(
      xob, wqkvT, b_qkv, TOKENS, 3072, 1024, nullptr, nullptr, nullptr, Qb, Kb, Vtb);
  // attention (512 blocks, 32 q-rows/wave — R9 measured best)
  attn_k<<<dim3(512), 256, 0, stream>>>(Qb, Kb, Vtb, xob);
  // out projection, split-K=2 -> raw fp32 partials (Qb/Kb dead now)
  gemm_bt<3, 64><<<dim3(1024 / 64, TOKENS / 128, 2), 256, 0, stream>>>(
      xob, woutT, b_out, TOKENS, 1024, 1024, pA0, pA1, nullptr, nullptr, nullptr, nullptr);
  // LN1 fused: pA0+pA1+b_out+x -> x1b (bf16 only; also serves as LN2 residual)
  ln_fused_k<0><<<TOKENS, 256, 0, stream>>>(pA0, pA1, b_out, x, ln1_g, ln1_b,
                                            nullptr, x1b);
  // FF1 + GELU (fast erf) — BN=64: grid 2048 = 8 blocks/CU
  gemm_bt<2, 64><<<dim3(4096 / 64, TOKENS / 128), 256, 0, stream>>>(
      x1b, wff1T, b_ff1, TOKENS, 4096, 1024, nullptr, nullptr, hb, nullptr, nullptr, nullptr);
  // FF2, split-K=2 (K=4096 -> 2x2048) -> partials
  gemm_bt<3, 64><<<dim3(1024 / 64, TOKENS / 128, 2), 256, 0, stream>>>(
      hb, wff2T, b_ff2, TOKENS, 1024, 4096, pB0, pB1, nullptr, nullptr, nullptr, nullptr);
  // LN2 fused: pB0+pB1+b_ff2+x1b(bf16) -> d_out
  ln_fused_k<1><<<TOKENS, 256, 0, stream>>>(pB0, pB1, b_ff2, x1b, ln2_g, ln2_b,
                                            out, nullptr);
}

// Round 16
// 251.510 us; speedup vs baseline: 1.1233x; 1.1233x over previous
//
#include <hip/hip_runtime.h>
#include <hip/hip_bf16.h>
#include <cstdint>
#include <cstddef>

using bf16 = __hip_bfloat16;
typedef __attribute__((ext_vector_type(8))) short bf16x8;
typedef __attribute__((ext_vector_type(4))) float f32x4;

#define TOKENS 4096
#define DMODEL 1024
#define DFF    4096
#define SEQ    2048
#define NHEAD  16
#define HDIM   64
#define KVBLK  64
#define NT     (SEQ / KVBLK)
#define QSCALE 0.1803368801111f   /* 0.125 * log2(e): folded into Q at QKV epilogue */

__device__ __forceinline__ void async16(const void* g, void* l) {
  __builtin_amdgcn_global_load_lds(
      (const __attribute__((address_space(1))) void*)g,
      (__attribute__((address_space(3))) void*)l, 16, 0, 0);
}

__device__ __forceinline__ f32x4 mfma16(bf16x8 a, bf16x8 b, f32x4 c) {
  return __builtin_amdgcn_mfma_f32_16x16x32_bf16(a, b, c, 0, 0, 0);
}

// native v_exp_f32: computes 2^x (single TRANS-pipe op, no OCML slow path)
__device__ __forceinline__ float exp2_fast(float x) {
  float r;
  asm("v_exp_f32 %0, %1" : "=v"(r) : "v"(x));
  return r;
}

// exact-GELU via A&S 7.1.26 erf (|eps| <= 1.5e-7), no library call
__device__ __forceinline__ float gelu_fast(float x) {
  const float z = fabsf(x) * 0.70710678118f;
  const float t = __builtin_amdgcn_rcpf(1.f + 0.3275911f * z);
  float p = 1.061405429f;
  p = p * t - 1.453152027f;
  p = p * t + 1.421413741f;
  p = p * t - 0.284496736f;
  p = p * t + 0.254829592f;
  const float e = exp2_fast(-z * z * 1.44269504089f);
  float erf = 1.f - p * t * e;
  erf = (x < 0.f) ? -erf : erf;
  return 0.5f * x * (1.f + erf);
}

// ---------------- fused prep: 4 weight transposes (fp32 KxN -> bf16 NxK) + x cast ----------------
__global__ __launch_bounds__(256)
void prep_k(const float* __restrict__ wqkv, const float* __restrict__ wout,
            const float* __restrict__ wff1, const float* __restrict__ wff2,
            bf16* __restrict__ dqkv, bf16* __restrict__ dout,
            bf16* __restrict__ dff1, bf16* __restrict__ dff2,
            const float* __restrict__ x, bf16* __restrict__ xb) {
  const int b = blockIdx.x, t = threadIdx.x;
  if (b >= 12288) {   // ---- cast x -> bf16 ----
    const int i = (b - 12288) * 1024 + t * 4;
    float4 v = *(const float4*)(x + i);
    bf16* d = xb + i;
    d[0] = __float2bfloat16(v.x); d[1] = __float2bfloat16(v.y);
    d[2] = __float2bfloat16(v.z); d[3] = __float2bfloat16(v.w);
    return;
  }
  const float* src; bf16* dst; int K, N, local;
  if (b < 3072)      { src = wqkv; dst = dqkv; K = 1024; N = 3072; local = b; }
  else if (b < 4096) { src = wout; dst = dout; K = 1024; N = 1024; local = b - 3072; }
  else if (b < 8192) { src = wff1; dst = dff1; K = 1024; N = 4096; local = b - 4096; }
  else               { src = wff2; dst = dff2; K = 4096; N = 1024; local = b - 8192; }
  const int nx = N >> 5;
  const int tiley = local / nx, tilex = local - tiley * nx;
  const int nt = tilex * 32, kt = tiley * 32;
  const int tx = t & 31, ty = t >> 5;   // 32 x 8
  __shared__ float tile[32][33];
  #pragma unroll
  for (int i = 0; i < 32; i += 8)
    tile[ty + i][tx] = src[(size_t)(kt + ty + i) * N + nt + tx];
  __syncthreads();
  #pragma unroll
  for (int i = 0; i < 32; i += 8)
    dst[(size_t)(nt + ty + i) * K + kt + tx] = __float2bfloat16(tile[tx][ty + i]);
}

// ---------------- GEMM: C[M][N] = A[M][K] * Bt[N][K] + bias, fused epilogue ----------------
// 2-phase pipeline (best-measured, R7/R8/R11/R14): double-buffered LDS,
// stage(t+1) issued BEFORE compute(t), single vmcnt(0)+barrier per K-tile, BK=32.
// BN=128 for big GEMMs (minimizes redundant A-panel fetch — R15 lesson);
// BN=64 + split-K=2 for the two narrow N=1024 GEMMs.
// EPI 0: QKV scatter (Q pre-scaled by QSCALE).  EPI 2: bf16 out = gelu(v).
// EPI 3: bf16 RAW split-K partial (halves partial traffic vs fp32; error
// budget: ~0.006 on LN input, margin 0.031 vs 0.1 threshold).
template <int EPI, int BN>
__global__ __launch_bounds__(256, 2)
void gemm_bt(const bf16* __restrict__ A, const bf16* __restrict__ Bt,
             const float* __restrict__ bias, int M, int N, int K,
             bf16* __restrict__ outp, bf16* __restrict__ outp2,
             bf16* __restrict__ outb,
             bf16* __restrict__ Qb, bf16* __restrict__ Kb, bf16* __restrict__ Vtb) {
  constexpr int MR = (BN == 128) ? 4 : 2;
  __shared__ bf16 Al[2][128 * 32];
  __shared__ bf16 Bl[2][BN * 32];
  const int t = threadIdx.x;
  const int nwg = gridDim.x * gridDim.y;
  const int flat = blockIdx.y * gridDim.x + blockIdx.x;
  const int swz = (flat & 7) * (nwg >> 3) + (flat >> 3);
  const int bm = (swz / gridDim.x) * 128, bn = (swz % gridDim.x) * BN;
  const int kz = blockIdx.z;
  const int Ksub = K / gridDim.z;
  const int kb0 = kz * Ksub;
  const int wid = t >> 6, lane = t & 63, g = lane >> 4, r = lane & 15;
  const int wr = (BN == 128) ? (wid >> 1) * 64 : wid * 32;
  const int wc = (BN == 128) ? (wid & 1) * 64 : 0;

  const f32x4 zero = {0.f, 0.f, 0.f, 0.f};
  f32x4 acc[MR][4];
  #pragma unroll
  for (int i = 0; i < MR; i++)
    #pragma unroll
    for (int j = 0; j < 4; j++) acc[i][j] = zero;

  const int ar0 = t >> 2, ac = (t & 3) * 8;
  const int ar1 = ar0 + 64;
  const int ach0 = t * 16, ach1 = ach0 + 4096;

  const int NK = Ksub >> 5;
  #define STAGE(ktile, pb)                                                          \
    do {                                                                            \
      const int kk = kb0 + ((ktile) << 5);                                          \
      async16(A + (size_t)(bm + ar0) * K + kk + ac, (char*)Al[pb] + ach0);          \
      async16(A + (size_t)(bm + ar1) * K + kk + ac, (char*)Al[pb] + ach1);          \
      async16(Bt + (size_t)(bn + ar0) * K + kk + ac, (char*)Bl[pb] + ach0);         \
      if constexpr (BN == 128)                                                      \
        async16(Bt + (size_t)(bn + ar1) * K + kk + ac, (char*)Bl[pb] + ach1);       \
    } while (0)

  STAGE(0, 0);
  asm volatile("s_waitcnt vmcnt(0)" ::: "memory");
  __builtin_amdgcn_s_barrier();

  #pragma unroll 1
  for (int it = 0; it < NK; ++it) {
    const int cur = it & 1;
    if (it + 1 < NK) STAGE(it + 1, cur ^ 1);
    bf16x8 af[MR], bfr[4];
    #pragma unroll
    for (int mt = 0; mt < MR; mt++)
      af[mt] = *(const bf16x8*)&Al[cur][(wr + mt * 16 + r) * 32 + 8 * g];
    #pragma unroll
    for (int nt = 0; nt < 4; nt++)
      bfr[nt] = *(const bf16x8*)&Bl[cur][(wc + nt * 16 + r) * 32 + 8 * g];
    #pragma unroll
    for (int mt = 0; mt < MR; mt++)
      #pragma unroll
      for (int nt = 0; nt < 4; nt++)
        acc[mt][nt] = mfma16(af[mt], bfr[nt], acc[mt][nt]);
    __builtin_amdgcn_sched_barrier(0);
    asm volatile("s_waitcnt vmcnt(0)" ::: "memory");
    __builtin_amdgcn_s_barrier();
  }
  #undef STAGE

  bf16* __restrict__ pdst = kz ? outp2 : outp;
  #pragma unroll
  for (int nt = 0; nt < 4; nt++) {
    const int col = bn + wc + nt * 16 + r;
    const float bv = (EPI == 3) ? 0.f : bias[col];
    #pragma unroll
    for (int mt = 0; mt < MR; mt++) {
      #pragma unroll
      for (int j = 0; j < 4; j++) {
        const int row = bm + wr + mt * 16 + 4 * g + j;
        float v = acc[mt][nt][j] + bv;
        if constexpr (EPI == 0) {
          const int part = col >> 10, hd = col & 1023, h = hd >> 6, d = hd & 63;
          const int b_ = row >> 11, s_ = row & 2047;
          if (part == 0) {
            Qb[((size_t)(b_ * NHEAD + h) * SEQ + s_) * HDIM + d] =
                __float2bfloat16(v * QSCALE);
          } else if (part == 1) {
            Kb[((size_t)(b_ * NHEAD + h) * SEQ + s_) * HDIM + d] = __float2bfloat16(v);
          } else {
            Vtb[((size_t)(b_ * NHEAD + h) * HDIM + d) * SEQ + s_] = __float2bfloat16(v);
          }
        } else if constexpr (EPI == 3) {
          pdst[(size_t)row * N + col] = __float2bfloat16(v);   // bf16 raw partial
        } else {
          outb[(size_t)row * N + col] = __float2bfloat16(gelu_fast(v));
        }
      }
    }
  }
}

// ---------------- flash attention (R9-measured best): LDS-staged, double-buffered ----------------
// grid 512 (XCD-chunked -> (bh,qb)), 256 thr = 4 waves, 32 q rows/wave (2 fragment
// sets of 16), KVBLK=64.  Q pre-scaled by 0.125*log2e -> softmax in exp2 domain
// (native v_exp_f32).  Defer-max (T13, THR=8) per set.
__global__ __launch_bounds__(256, 3)
void attn_k(const bf16* __restrict__ Q, const bf16* __restrict__ Km,
            const bf16* __restrict__ Vt, bf16* __restrict__ O) {
  __shared__ bf16 Kl[2][KVBLK * 64];   // 16 KB
  __shared__ bf16 Vl[2][KVBLK * 64];   // 16 KB
  __shared__ bf16 P[4][32 * 64];       // 16 KB: per-wave 32-row P, XOR-swizzled
  const int b = blockIdx.x;
  const int bswz = (b & 7) * 64 + (b >> 3);   // 512 blocks, 64/XCD -> 4 heads/XCD
  const int bh = bswz >> 4, qb = bswz & 15;
  const int t = threadIdx.x, wid = t >> 6, lane = t & 63, g = lane >> 4, r = lane & 15;
  const int q0 = qb * 128 + wid * 32;
  const bf16* Qp = Q + (size_t)bh * SEQ * HDIM;
  const char* Kc = (const char*)(Km + (size_t)bh * SEQ * HDIM);
  const char* Vc = (const char*)(Vt + (size_t)bh * HDIM * SEQ);

  bf16x8 qf[2][2];
  #pragma unroll
  for (int s = 0; s < 2; s++) {
    qf[s][0] = *(const bf16x8*)&Qp[(q0 + 16 * s + r) * HDIM + 8 * g];
    qf[s][1] = *(const bf16x8*)&Qp[(q0 + 16 * s + r) * HDIM + 8 * g + 32];
  }

  const int o0 = wid * 2048 + lane * 16, o1 = o0 + 1024;
  const int cs0 = ((((o0 >> 4) & 7) ^ ((o0 >> 7) & 7)) << 4);
  const int cs1 = ((((o1 >> 4) & 7) ^ ((o1 >> 7) & 7)) << 4);
  const int kso0 = (o0 & ~127) + cs0, kso1 = (o1 & ~127) + cs1;
  const int vso0 = (o0 >> 7) * (SEQ * 2) + cs0, vso1 = (o1 >> 7) * (SEQ * 2) + cs1;

  const f32x4 zero = {0.f, 0.f, 0.f, 0.f};
  f32x4 oacc[2][4];
  #pragma unroll
  for (int s = 0; s < 2; s++)
    #pragma unroll
    for (int i = 0; i < 4; i++) oacc[s][i] = zero;
  float mrow[2] = {-1e30f, -1e30f}, lrow[2] = {0.f, 0.f};
  bf16* pl = P[wid];
  const int cA = ((g ^ (r & 7)) << 3), cB = (((g + 4) ^ (r & 7)) << 3);

  {
    char* kd = (char*)Kl[0]; char* vd = (char*)Vl[0];
    async16(Kc + kso0, kd + o0); async16(Kc + kso1, kd + o1);
    async16(Vc + vso0, vd + o0); async16(Vc + vso1, vd + o1);
  }

  #pragma unroll 1
  for (int tt = 0; tt < NT; ++tt) {
    if (tt + 1 < NT) {
      const char* ks = Kc + (tt + 1) * (KVBLK * HDIM * 2);
      const char* vs = Vc + (tt + 1) * (KVBLK * 2);
      char* kd = (char*)Kl[(tt + 1) & 1]; char* vd = (char*)Vl[(tt + 1) & 1];
      async16(ks + kso0, kd + o0); async16(ks + kso1, kd + o1);
      async16(vs + vso0, vd + o0); async16(vs + vso1, vd + o1);
      asm volatile("s_waitcnt vmcnt(4)" ::: "memory");
    } else {
      asm volatile("s_waitcnt vmcnt(0)" ::: "memory");
    }
    __builtin_amdgcn_sched_barrier(0);
    __builtin_amdgcn_s_barrier();
    __builtin_amdgcn_sched_barrier(0);

    const bf16* kbuf = Kl[tt & 1];
    const bf16* vbuf = Vl[tt & 1];

    // ---- QK^T (swapped): each K fragment pair feeds BOTH q-sets ----
    f32x4 sacc[2][4];
    #pragma unroll
    for (int kt = 0; kt < 4; kt++) {
      const bf16* krow = kbuf + (kt * 16 + r) * 64;
      bf16x8 ka = *(const bf16x8*)&krow[cA];
      bf16x8 kb = *(const bf16x8*)&krow[cB];
      #pragma unroll
      for (int s = 0; s < 2; s++) {
        f32x4 sc = mfma16(ka, qf[s][0], zero);
        sacc[s][kt] = mfma16(kb, qf[s][1], sc);
      }
    }

    // ---- per-set softmax (exp2 domain) + P write ----
    bool grow[2];
    float corr[2];
    #pragma unroll
    for (int s = 0; s < 2; s++) {
      float m0 = fmaxf(fmaxf(sacc[s][0][0], sacc[s][0][1]), fmaxf(sacc[s][0][2], sacc[s][0][3]));
      float m1 = fmaxf(fmaxf(sacc[s][1][0], sacc[s][1][1]), fmaxf(sacc[s][1][2], sacc[s][1][3]));
      float m2 = fmaxf(fmaxf(sacc[s][2][0], sacc[s][2][1]), fmaxf(sacc[s][2][2], sacc[s][2][3]));
      float m3 = fmaxf(fmaxf(sacc[s][3][0], sacc[s][3][1]), fmaxf(sacc[s][3][2], sacc[s][3][3]));
      float mx = fmaxf(fmaxf(m0, m1), fmaxf(m2, m3));
      mx = fmaxf(mx, __shfl_xor(mx, 16));
      mx = fmaxf(mx, __shfl_xor(mx, 32));
      grow[s] = !__all(mx <= mrow[s] + 8.f);
      corr[s] = 1.f;
      if (grow[s]) {
        const float mn = fmaxf(mrow[s], mx);
        corr[s] = exp2_fast(mrow[s] - mn);
        mrow[s] = mn;
      }
      float sum = 0.f;
      #pragma unroll
      for (int kt = 0; kt < 4; kt++) {
        bf16 pk[4];
        #pragma unroll
        for (int j = 0; j < 4; j++) {
          const float p = exp2_fast(sacc[s][kt][j] - mrow[s]);
          pk[j] = __float2bfloat16(p);
          sum += p;
        }
        const int pc = (((kt * 2 + (g >> 1)) ^ (r & 7)) << 4) + ((g & 1) << 3);
        *(short4*)((char*)pl + (16 * s + r) * 128 + pc) = *(const short4*)pk;
      }
      sum += __shfl_xor(sum, 16);
      sum += __shfl_xor(sum, 32);
      lrow[s] = lrow[s] * corr[s] + sum;
    }

    asm volatile("s_waitcnt lgkmcnt(0)" ::: "memory");
    __builtin_amdgcn_sched_barrier(0);
    bf16x8 pf[2][2];
    #pragma unroll
    for (int s = 0; s < 2; s++) {
      pf[s][0] = *(const bf16x8*)((const char*)pl + (16 * s + r) * 128 + (cA << 1));
      pf[s][1] = *(const bf16x8*)((const char*)pl + (16 * s + r) * 128 + (cB << 1));
    }

    #pragma unroll
    for (int s = 0; s < 2; s++) {
      if (grow[s]) {   // wave-uniform: rescale O only when this set's max grew
        float cq[4];
        #pragma unroll
        for (int j = 0; j < 4; j++) cq[j] = __shfl(corr[s], 4 * g + j);
        #pragma unroll
        for (int dt = 0; dt < 4; dt++)
          #pragma unroll
          for (int j = 0; j < 4; j++) oacc[s][dt][j] *= cq[j];
      }
    }

    // ---- PV: each V fragment pair feeds BOTH q-sets ----
    #pragma unroll
    for (int dt = 0; dt < 4; dt++) {
      const bf16* vrow = vbuf + (dt * 16 + r) * 64;
      bf16x8 v0 = *(const bf16x8*)&vrow[cA];
      bf16x8 v1 = *(const bf16x8*)&vrow[cB];
      #pragma unroll
      for (int s = 0; s < 2; s++) {
        oacc[s][dt] = mfma16(pf[s][0], v0, oacc[s][dt]);
        oacc[s][dt] = mfma16(pf[s][1], v1, oacc[s][dt]);
      }
    }
    __builtin_amdgcn_sched_barrier(0);
    __builtin_amdgcn_s_barrier();
  }

  const int b_ = bh >> 4, h = bh & 15;
  #pragma unroll
  for (int s = 0; s < 2; s++) {
    float lq[4];
    #pragma unroll
    for (int j = 0; j < 4; j++) lq[j] = __shfl(lrow[s], 4 * g + j);
    #pragma unroll
    for (int dt = 0; dt < 4; dt++)
      #pragma unroll
      for (int j = 0; j < 4; j++) {
        const int tok = b_ * SEQ + q0 + 16 * s + 4 * g + j;
        O[(size_t)tok * DMODEL + h * HDIM + dt * 16 + r] =
            __float2bfloat16(oacc[s][dt][j] / lq[j]);
      }
  }
}

// ---------------- fused split-K reduce + bias + residual + LayerNorm ----------------
// Partials p0/p1 are bf16.  RB=0: resid fp32; RB=1: resid bf16.
// v = p0+p1+bias2+resid; LN(v)*g+b.
template <int RB>
__global__ __launch_bounds__(256)
void ln_fused_k(const bf16* __restrict__ p0, const bf16* __restrict__ p1,
                const float* __restrict__ bias2, const void* __restrict__ resid,
                const float* __restrict__ gw, const float* __restrict__ bw,
                float* __restrict__ outf, bf16* __restrict__ outb) {
  const int row = blockIdx.x, t = threadIdx.x;
  const size_t base = (size_t)row * DMODEL + t * 4;
  const short4 a4 = *(const short4*)(p0 + base);
  const short4 b4 = *(const short4*)(p1 + base);
  float a0 = __bfloat162float(((const bf16*)&a4)[0]);
  float a1 = __bfloat162float(((const bf16*)&a4)[1]);
  float a2 = __bfloat162float(((const bf16*)&a4)[2]);
  float a3 = __bfloat162float(((const bf16*)&a4)[3]);
  float b0 = __bfloat162float(((const bf16*)&b4)[0]);
  float b1 = __bfloat162float(((const bf16*)&b4)[1]);
  float b2 = __bfloat162float(((const bf16*)&b4)[2]);
  float b3 = __bfloat162float(((const bf16*)&b4)[3]);
  float rr0, rr1, rr2, rr3;
  if constexpr (RB) {
    const short4 rv = *(const short4*)((const bf16*)resid + base);
    rr0 = __bfloat162float(((const bf16*)&rv)[0]);
    rr1 = __bfloat162float(((const bf16*)&rv)[1]);
    rr2 = __bfloat162float(((const bf16*)&rv)[2]);
    rr3 = __bfloat162float(((const bf16*)&rv)[3]);
  } else {
    const float4 rv = *(const float4*)((const float*)resid + base);
    rr0 = rv.x; rr1 = rv.y; rr2 = rv.z; rr3 = rv.w;
  }
  const float4 bb = *(const float4*)(bias2 + t * 4);
  float4 v;
  v.x = a0 + b0 + rr0 + bb.x;
  v.y = a1 + b1 + rr1 + bb.y;
  v.z = a2 + b2 + rr2 + bb.z;
  v.w = a3 + b3 + rr3 + bb.w;
  float s = v.x + v.y + v.z + v.w;
  float s2 = v.x * v.x + v.y * v.y + v.z * v.z + v.w * v.w;
  #pragma unroll
  for (int m = 1; m < 64; m <<= 1) { s += __shfl_xor(s, m); s2 += __shfl_xor(s2, m); }
  __shared__ float red[8];
  const int wid = t >> 6, lane = t & 63;
  if (lane == 0) { red[wid] = s; red[4 + wid] = s2; }
  __syncthreads();
  s = red[0] + red[1] + red[2] + red[3];
  s2 = red[4] + red[5] + red[6] + red[7];
  const float mu = s * (1.f / DMODEL);
  const float rstd = rsqrtf(s2 * (1.f / DMODEL) - mu * mu + 1e-5f);
  const float4 gv = *(const float4*)(gw + t * 4);
  const float4 bv = *(const float4*)(bw + t * 4);
  float o0 = (v.x - mu) * rstd * gv.x + bv.x;
  float o1 = (v.y - mu) * rstd * gv.y + bv.y;
  float o2 = (v.z - mu) * rstd * gv.z + bv.z;
  float o3 = (v.w - mu) * rstd * gv.w + bv.w;
  if (outf) {
    float4 ov = {o0, o1, o2, o3};
    *(float4*)(outf + base) = ov;
  }
  if (outb) {
    bf16* p = outb + base;
    p[0] = __float2bfloat16(o0); p[1] = __float2bfloat16(o1);
    p[2] = __float2bfloat16(o2); p[3] = __float2bfloat16(o3);
  }
}

extern "C" void kernel_launch(void* const* d_in, const int* in_sizes, int n_in,
                              void* d_out, int out_size, void* d_ws, size_t ws_size,
                              hipStream_t stream) {
  const float* x     = (const float*)d_in[0];
  const float* w_qkv = (const float*)d_in[1];
  const float* b_qkv = (const float*)d_in[2];
  const float* w_out = (const float*)d_in[3];
  const float* b_out = (const float*)d_in[4];
  const float* w_ff1 = (const float*)d_in[5];
  const float* b_ff1 = (const float*)d_in[6];
  const float* w_ff2 = (const float*)d_in[7];
  const float* b_ff2 = (const float*)d_in[8];
  const float* ln1_g = (const float*)d_in[9];
  const float* ln1_b = (const float*)d_in[10];
  const float* ln2_g = (const float*)d_in[11];
  const float* ln2_b = (const float*)d_in[12];
  float* out = (float*)d_out;

  // workspace layout (heavy aliasing; all stream-ordered):
  //   [0,16M)      wqkvT+woutT+wff1T  -> later FF2 bf16 partial p1 (dead by then)
  //   [24M,56M)    Qb/Kb/Vtb/xob      -> Qb reused as out-proj bf16 partial p0; hb aliases
  //   [56M,72M)    y region: out-proj bf16 partial p1, then FF2 bf16 partial p0
  //   [88M,96M)    x1b (LN1 output, bf16 — also LN2 residual)
  char* base = (char*)d_ws;
  bf16* wqkvT = (bf16*)(base);                 //  6291456 : 3072x1024
  bf16* woutT = (bf16*)(base + 6291456);       //  2097152 : 1024x1024
  bf16* wff1T = (bf16*)(base + 8388608);       //  8388608 : 4096x1024
  bf16* wff2T = (bf16*)(base + 16777216);      //  8388608 : 1024x4096
  bf16* Qb    = (bf16*)(base + 25165824);      //  8388608
  bf16* Kb    = (bf16*)(base + 33554432);      //  8388608
  bf16* Vtb   = (bf16*)(base + 41943040);      //  8388608
  bf16* xob   = (bf16*)(base + 50331648);      //  8388608 : x_bf16, later attn-out bf16
  bf16* hb    = (bf16*)(base + 25165824);      // 33554432 : aliases Qb..xob (dead by FF1)
  bf16* pA0   = (bf16*)(base + 25165824);      //  8388608 : out-proj bf16 partial 0 (over Qb)
  bf16* pA1   = (bf16*)(base + 58720256);      //  8388608 : out-proj bf16 partial 1
  bf16* pB0   = (bf16*)(base + 58720256);      //  8388608 : FF2 bf16 partial 0
  bf16* pB1   = (bf16*)(base);                 //  8388608 : FF2 bf16 partial 1 (over weights)
  bf16* x1b   = (bf16*)(base + 92274688);      //  8388608
  (void)in_sizes; (void)n_in; (void)out_size; (void)ws_size;

  // fused prep: all 4 weight transposes + x cast in ONE launch
  prep_k<<<dim3(16384), 256, 0, stream>>>(w_qkv, w_out, w_ff1, w_ff2,
                                          wqkvT, woutT, wff1T, wff2T, x, xob);

  // QKV projection + scatter (Q pre-scaled) — BN=128 (R14 measured best)
  gemm_bt<0, 128><<<dim3(3072 / 128, TOKENS / 128), 256, 0, stream>>>(
      xob, wqkvT, b_qkv, TOKENS, 3072, 1024, nullptr, nullptr, nullptr, Qb, Kb, Vtb);
  // attention (512 blocks, 32 q-rows/wave — R9 measured best)
  attn_k<<<dim3(512), 256, 0, stream>>>(Qb, Kb, Vtb, xob);
  // out projection, split-K=2 -> bf16 raw partials (Qb dead now)
  gemm_bt<3, 64><<<dim3(1024 / 64, TOKENS / 128, 2), 256, 0, stream>>>(
      xob, woutT, b_out, TOKENS, 1024, 1024, pA0, pA1, nullptr, nullptr, nullptr, nullptr);
  // LN1 fused: pA0+pA1+b_out+x -> x1b (bf16 only; also serves as LN2 residual)
  ln_fused_k<0><<<TOKENS, 256, 0, stream>>>(pA0, pA1, b_out, x, ln1_g, ln1_b,
                                            nullptr, x1b);
  // FF1 + GELU (fast erf) — BN=128 (R14 measured best)
  gemm_bt<2, 128><<<dim3(4096 / 128, TOKENS / 128), 256, 0, stream>>>(
      x1b, wff1T, b_ff1, TOKENS, 4096, 1024, nullptr, nullptr, hb, nullptr, nullptr, nullptr);
  // FF2, split-K=2 (K=4096 -> 2x2048) -> bf16 partials
  gemm_bt<3, 64><<<dim3(1024 / 64, TOKENS / 128, 2), 256, 0, stream>>>(
      hb, wff2T, b_ff2, TOKENS, 1024, 4096, pB0, pB1, nullptr, nullptr, nullptr, nullptr);
  // LN2 fused: pB0+pB1+b_ff2+x1b(bf16) -> d_out
  ln_fused_k<1><<<TOKENS, 256, 0, stream>>>(pB0, pB1, b_ff2, x1b, ln2_g, ln2_b,
                                            out, nullptr);
}